// Round 6
// baseline (739.557 us; speedup 1.0000x reference)
//
#include <hip/hip_runtime.h>

typedef __attribute__((ext_vector_type(8))) short  short8;
typedef __attribute__((ext_vector_type(4))) float  f32x4;
typedef __attribute__((ext_vector_type(4))) ushort us4;
typedef __attribute__((ext_vector_type(4))) uint   u32x4;

__device__ __forceinline__ float bf2f(ushort u) {
    union { uint i; float f; } c; c.i = ((uint)u) << 16; return c.f;
}
__device__ __forceinline__ ushort f2bf(float f) {
    union { float f; uint i; } c; c.f = f;
    uint b = c.i + 0x7fffu + ((c.i >> 16) & 1u);   // RNE, no NaN inputs here
    return (ushort)(b >> 16);
}

// ================= normalization + CSR build =================

__global__ void k_deg_init(float* deg, int* cnt, int n) {
    int i = blockIdx.x * blockDim.x + threadIdx.x;
    if (i < n) { deg[i] = 1.0f; cnt[i] = 0; }   // deg starts at 1.0 (self loop)
}

__global__ void k_deg_count(const int* __restrict__ col, const float* __restrict__ w,
                            float* __restrict__ deg, int* __restrict__ cnt, int E) {
    int i = blockIdx.x * blockDim.x + threadIdx.x;
    if (i < E) {
        int c = col[i];
        atomicAdd(&deg[c], w[i]);
        atomicAdd(&cnt[c], 1);
    }
}

__global__ void k_dinv(float* deg, int n) {
    int i = blockIdx.x * blockDim.x + threadIdx.x;
    if (i < n) {
        float d = deg[i];
        deg[i] = d > 0.0f ? rsqrtf(d) : 0.0f;
    }
}

__global__ void k_scan_bsum(const int* __restrict__ cnt, int* __restrict__ bsum, int N) {
    __shared__ int sdata[256];
    int base = blockIdx.x * 1024;
    int t = threadIdx.x;
    int s = 0;
    #pragma unroll
    for (int j = 0; j < 4; ++j) { int i = base + t * 4 + j; if (i < N) s += cnt[i]; }
    sdata[t] = s; __syncthreads();
    for (int off = 128; off > 0; off >>= 1) {
        if (t < off) sdata[t] += sdata[t + off];
        __syncthreads();
    }
    if (t == 0) bsum[blockIdx.x] = sdata[0];
}

__global__ void k_scan_boff(int* __restrict__ bsum, int nb, int* __restrict__ total) {
    __shared__ int buf[256];
    int t = threadIdx.x;
    int v = (t < nb) ? bsum[t] : 0;
    buf[t] = v; __syncthreads();
    for (int off = 1; off < 256; off <<= 1) {
        int x = (t >= off) ? buf[t - off] : 0;
        __syncthreads();
        buf[t] += x;
        __syncthreads();
    }
    if (t < nb) bsum[t] = buf[t] - v;
    if (t == nb - 1) *total = buf[t];
}

__global__ void k_scan_write(const int* __restrict__ cnt, const int* __restrict__ bsum,
                             int* __restrict__ rowptr, int* __restrict__ cursor, int N) {
    __shared__ int sdata[256];
    int base = blockIdx.x * 1024;
    int t = threadIdx.x;
    int c[4]; int s = 0;
    #pragma unroll
    for (int j = 0; j < 4; ++j) {
        int i = base + t * 4 + j;
        c[j] = (i < N) ? cnt[i] : 0;
        s += c[j];
    }
    sdata[t] = s; __syncthreads();
    for (int off = 1; off < 256; off <<= 1) {
        int x = (t >= off) ? sdata[t - off] : 0;
        __syncthreads();
        sdata[t] += x;
        __syncthreads();
    }
    int excl = sdata[t] - s + bsum[blockIdx.x];
    #pragma unroll
    for (int j = 0; j < 4; ++j) {
        int i = base + t * 4 + j;
        if (i < N) { rowptr[i] = excl; cursor[i] = excl; }
        excl += c[j];
    }
}

// Scatter edges into dst-sorted CSR as packed records: low16 = src row (N<=65536),
// high16 = bf16(norm).
__global__ void k_scatter(const int* __restrict__ row, const int* __restrict__ col,
                          const float* __restrict__ w, const float* __restrict__ dinv,
                          int* __restrict__ cursor, uint* __restrict__ edges, int E) {
    int i = blockIdx.x * blockDim.x + threadIdx.x;
    if (i < E) {
        int r = row[i], c = col[i];
        int p = atomicAdd(&cursor[c], 1);
        float nv = dinv[r] * w[i] * dinv[c];
        edges[p] = (uint)(ushort)r | ((uint)f2bf(nv) << 16);
    }
}

// ================= weight split + transpose: W[K][N] -> WT{h,l}[N][K] ==========
__global__ void k_splitT(const float* __restrict__ W, ushort* __restrict__ Th,
                         ushort* __restrict__ Tl, int K, int N) {
    int i = blockIdx.x * 256 + threadIdx.x;
    if (i < K * N) {
        int k = i / N, n = i - k * N;
        float v = W[i];
        ushort hi = f2bf(v);
        ushort lo = f2bf(v - bf2f(hi));
        Th[(size_t)n * K + k] = hi;
        Tl[(size_t)n * K + k] = lo;
    }
}

// ================= MFMA GEMM: h_pan[panel][m][32] = bf16(A_f32[M,K] @ W[K,Nc]) ==
#define LDA 40   // padded LDS row stride (bf16 elems)

__global__ __launch_bounds__(256)
void k_gemm3(const float* __restrict__ A, const ushort* __restrict__ BTh,
             const ushort* __restrict__ BTl, ushort* __restrict__ Cpan,
             int M, int Nc, int K) {
    __shared__ __align__(16) ushort As[2][128][LDA];
    __shared__ __align__(16) ushort Bs[2][64][LDA];

    const int t    = threadIdx.x;
    const int lane = t & 63;
    const int wid  = t >> 6;
    const int wm   = wid >> 1;
    const int wn   = wid & 1;
    const int ml   = lane & 15;
    const int kq   = lane >> 4;
    const int bm   = blockIdx.y * 128;
    const int bn   = blockIdx.x * 64;

    f32x4 acc[4][2];
    #pragma unroll
    for (int mt = 0; mt < 4; ++mt)
        #pragma unroll
        for (int nt = 0; nt < 2; ++nt) acc[mt][nt] = (f32x4){0.f, 0.f, 0.f, 0.f};

    for (int k0 = 0; k0 < K; k0 += 32) {
        #pragma unroll
        for (int it = 0; it < 4; ++it) {
            int idx = (t + it * 256) * 4;
            int r  = idx >> 5;
            int kk = idx & 31;
            int grow = bm + r;
            f32x4 v = (f32x4){0.f, 0.f, 0.f, 0.f};
            if (grow < M) v = *(const f32x4*)&A[(size_t)grow * K + k0 + kk];
            us4 hi, lo;
            #pragma unroll
            for (int j = 0; j < 4; ++j) {
                ushort h = f2bf(v[j]);
                hi[j] = h;
                lo[j] = f2bf(v[j] - bf2f(h));
            }
            *(us4*)&As[0][r][kk] = hi;
            *(us4*)&As[1][r][kk] = lo;
        }
        {
            int idx = t * 8;
            int n  = idx >> 5;
            int kk = idx & 31;
            u32x4 vh = *(const u32x4*)&BTh[(size_t)(bn + n) * K + k0 + kk];
            *(u32x4*)&Bs[0][n][kk] = vh;
            u32x4 vl = *(const u32x4*)&BTl[(size_t)(bn + n) * K + k0 + kk];
            *(u32x4*)&Bs[1][n][kk] = vl;
        }
        __syncthreads();

        short8 a[4][2], b[2][2];
        #pragma unroll
        for (int mt = 0; mt < 4; ++mt) {
            a[mt][0] = *(const short8*)&As[0][wm * 64 + mt * 16 + ml][kq * 8];
            a[mt][1] = *(const short8*)&As[1][wm * 64 + mt * 16 + ml][kq * 8];
        }
        #pragma unroll
        for (int nt = 0; nt < 2; ++nt) {
            b[nt][0] = *(const short8*)&Bs[0][wn * 32 + nt * 16 + ml][kq * 8];
            b[nt][1] = *(const short8*)&Bs[1][wn * 32 + nt * 16 + ml][kq * 8];
        }
        #pragma unroll
        for (int mt = 0; mt < 4; ++mt)
            #pragma unroll
            for (int nt = 0; nt < 2; ++nt) {
                acc[mt][nt] = __builtin_amdgcn_mfma_f32_16x16x32_bf16(a[mt][0], b[nt][0], acc[mt][nt], 0, 0, 0);
                acc[mt][nt] = __builtin_amdgcn_mfma_f32_16x16x32_bf16(a[mt][0], b[nt][1], acc[mt][nt], 0, 0, 0);
                acc[mt][nt] = __builtin_amdgcn_mfma_f32_16x16x32_bf16(a[mt][1], b[nt][0], acc[mt][nt], 0, 0, 0);
            }
        __syncthreads();
    }

    #pragma unroll
    for (int mt = 0; mt < 4; ++mt) {
        int rbase = bm + wm * 64 + mt * 16 + kq * 4;
        #pragma unroll
        for (int nt = 0; nt < 2; ++nt) {
            int colg = bn + wn * 32 + nt * 16 + ml;
            size_t pbase = (size_t)(colg >> 5) * M * 32 + (colg & 31);
            #pragma unroll
            for (int r = 0; r < 4; ++r) {
                int rr = rbase + r;
                if (rr < M) Cpan[pbase + (size_t)rr * 32] = f2bf(acc[mt][nt][r]);
            }
        }
    }
}

// ================= panel CSR aggregation ======================================
// h_pan: [npan][N][32] bf16. out: row-major [N][F] fp32.
// 4x-unrolled edge loop: 4 independent NT edge loads then 4 independent gathers
// in flight -> amortize the dependent-chain latency (R5 was latency-bound).
#define NODES_PER_CHUNK 16

template <bool RELU>
__global__ __launch_bounds__(256)
void k_aggr_pan(const int* __restrict__ rowptr, const uint* __restrict__ edges,
                const ushort* __restrict__ hpan, const float* __restrict__ dinv,
                const float* __restrict__ bias, float* __restrict__ out,
                int F, int npan, int N) {
    const int bid   = blockIdx.x;
    const int p     = bid % npan;
    const int chunk = bid / npan;
    const int wave  = threadIdx.x >> 6;
    const int lane  = threadIdx.x & 63;
    const int sub   = lane >> 3;
    const int q     = lane & 7;

    const ushort* hp = hpan + (size_t)p * N * 32;
    const int fbase = p * 32 + q * 4;
    f32x4 bv = *(const f32x4*)&bias[fbase];

    #pragma unroll
    for (int i = 0; i < NODES_PER_CHUNK / 4; ++i) {
        int node = chunk * NODES_PER_CHUNK + i * 4 + wave;
        if (node >= N) return;
        int beg = rowptr[node], end = rowptr[node + 1];

        f32x4 acc = (f32x4){0.f, 0.f, 0.f, 0.f};
        int e = beg + sub;
        // main: 4 edges per sub in flight (covers [beg+32k, beg+32k+32))
        for (; e + 24 < end; e += 32) {
            uint pk0 = __builtin_nontemporal_load(&edges[e]);
            uint pk1 = __builtin_nontemporal_load(&edges[e + 8]);
            uint pk2 = __builtin_nontemporal_load(&edges[e + 16]);
            uint pk3 = __builtin_nontemporal_load(&edges[e + 24]);
            const us4* g0 = (const us4*)&hp[(size_t)(pk0 & 0xffffu) * 32 + q * 4];
            const us4* g1 = (const us4*)&hp[(size_t)(pk1 & 0xffffu) * 32 + q * 4];
            const us4* g2 = (const us4*)&hp[(size_t)(pk2 & 0xffffu) * 32 + q * 4];
            const us4* g3 = (const us4*)&hp[(size_t)(pk3 & 0xffffu) * 32 + q * 4];
            us4 h0 = *g0, h1 = *g1, h2 = *g2, h3 = *g3;
            float n0 = bf2f((ushort)(pk0 >> 16));
            float n1 = bf2f((ushort)(pk1 >> 16));
            float n2 = bf2f((ushort)(pk2 >> 16));
            float n3 = bf2f((ushort)(pk3 >> 16));
            #pragma unroll
            for (int j = 0; j < 4; ++j) {
                acc[j] += n0 * bf2f(h0[j]);
                acc[j] += n1 * bf2f(h1[j]);
                acc[j] += n2 * bf2f(h2[j]);
                acc[j] += n3 * bf2f(h3[j]);
            }
        }
        // tail: stride-8 scalar
        for (; e < end; e += 8) {
            uint pk = __builtin_nontemporal_load(&edges[e]);
            float nv = bf2f((ushort)(pk >> 16));
            us4 hv = *(const us4*)&hp[(size_t)(pk & 0xffffu) * 32 + q * 4];
            #pragma unroll
            for (int j = 0; j < 4; ++j) acc[j] += nv * bf2f(hv[j]);
        }
        // reduce over sub (lane bits 3,4,5)
        #pragma unroll
        for (int m = 8; m <= 32; m <<= 1) {
            acc[0] += __shfl_xor(acc[0], m, 64);
            acc[1] += __shfl_xor(acc[1], m, 64);
            acc[2] += __shfl_xor(acc[2], m, 64);
            acc[3] += __shfl_xor(acc[3], m, 64);
        }
        if (sub == 0) {
            float di = dinv[node];
            float d2 = di * di;
            us4 hs = *(const us4*)&hp[(size_t)node * 32 + q * 4];
            f32x4 v;
            v[0] = acc[0] + d2 * bf2f(hs[0]) + bv[0];
            v[1] = acc[1] + d2 * bf2f(hs[1]) + bv[1];
            v[2] = acc[2] + d2 * bf2f(hs[2]) + bv[2];
            v[3] = acc[3] + d2 * bf2f(hs[3]) + bv[3];
            if (RELU) {
                v[0] = fmaxf(v[0], 0.f); v[1] = fmaxf(v[1], 0.f);
                v[2] = fmaxf(v[2], 0.f); v[3] = fmaxf(v[3], 0.f);
            }
            *(f32x4*)&out[(size_t)node * F + fbase] = v;
        }
    }
}

// ================= launcher =================

static inline char* bump(char*& p, size_t bytes) {
    char* r = p;
    p += (bytes + 255) & ~(size_t)255;
    return r;
}

extern "C" void kernel_launch(void* const* d_in, const int* in_sizes, int n_in,
                              void* d_out, int out_size, void* d_ws, size_t ws_size,
                              hipStream_t stream) {
    const float* x  = (const float*)d_in[0];
    const int*   ei = (const int*)d_in[1];
    const float* ew = (const float*)d_in[2];
    const float* W1 = (const float*)d_in[3];
    const float* b1 = (const float*)d_in[4];
    const float* W2 = (const float*)d_in[5];
    const float* b2 = (const float*)d_in[6];
    float* out = (float*)d_out;

    const int E    = in_sizes[2];
    const int H    = in_sizes[4];       // 256
    const int Fout = in_sizes[6];       // 128
    const int Fin  = in_sizes[3] / H;   // 256
    const int N    = in_sizes[0] / Fin; // 50000 (fits ushort)

    const int* row = ei;
    const int* col = ei + E;

    char* p = (char*)d_ws;
    float*  dinv   = (float*)bump(p, (size_t)N * 4);
    int*    rowptr = (int*)bump(p, (size_t)(N + 1) * 4);
    int*    cursor = (int*)bump(p, (size_t)N * 4);
    int*    cnt    = (int*)bump(p, (size_t)N * 4);
    uint*   edges  = (uint*)bump(p, (size_t)E * 4);
    ushort* WT1h   = (ushort*)bump(p, (size_t)Fin * H * 2);
    ushort* WT1l   = (ushort*)bump(p, (size_t)Fin * H * 2);
    ushort* WT2h   = (ushort*)bump(p, (size_t)H * Fout * 2);
    ushort* WT2l   = (ushort*)bump(p, (size_t)H * Fout * 2);
    ushort* h1     = (ushort*)bump(p, (size_t)N * H * 2);     // panel-major bf16
    float*  a1     = (float*)bump(p, (size_t)N * H * 4);      // row-major fp32
    ushort* h2     = (ushort*)bump(p, (size_t)N * Fout * 2);  // panel-major bf16

    const int nb = (N + 1023) / 1024;

    k_deg_init<<<(N + 255) / 256, 256, 0, stream>>>(dinv, cnt, N);
    k_deg_count<<<(E + 255) / 256, 256, 0, stream>>>(col, ew, dinv, cnt, E);
    k_dinv<<<(N + 255) / 256, 256, 0, stream>>>(dinv, N);

    k_splitT<<<(Fin * H + 255) / 256, 256, 0, stream>>>(W1, WT1h, WT1l, Fin, H);
    k_splitT<<<(H * Fout + 255) / 256, 256, 0, stream>>>(W2, WT2h, WT2l, H, Fout);

    k_scan_bsum<<<nb, 256, 0, stream>>>(cnt, cursor, N);
    k_scan_boff<<<1, 256, 0, stream>>>(cursor, nb, rowptr + N);
    k_scan_write<<<nb, 256, 0, stream>>>(cnt, cursor, rowptr, cnt, N);
    k_scatter<<<(E + 255) / 256, 256, 0, stream>>>(row, col, ew, dinv, cnt, edges, E);

    const int chunks = (N + NODES_PER_CHUNK - 1) / NODES_PER_CHUNK;

    // layer 1
    k_gemm3<<<dim3(H / 64, (N + 127) / 128), 256, 0, stream>>>(x, WT1h, WT1l, h1, N, H, Fin);
    k_aggr_pan<true><<<chunks * (H / 32), 256, 0, stream>>>(rowptr, edges, h1, dinv, b1, a1, H, H / 32, N);

    // layer 2
    k_gemm3<<<dim3(Fout / 64, (N + 127) / 128), 256, 0, stream>>>(a1, WT2h, WT2l, h2, N, Fout, H);
    k_aggr_pan<false><<<chunks * (Fout / 32), 256, 0, stream>>>(rowptr, edges, h2, dinv, b2, out, Fout, Fout / 32, N);
}

// Round 7
// 652.669 us; speedup vs baseline: 1.1331x; 1.1331x over previous
//
#include <hip/hip_runtime.h>

typedef __attribute__((ext_vector_type(8))) short  short8;
typedef __attribute__((ext_vector_type(4))) float  f32x4;
typedef __attribute__((ext_vector_type(4))) ushort us4;
typedef __attribute__((ext_vector_type(4))) uint   u32x4;

__device__ __forceinline__ float bf2f(ushort u) {
    union { uint i; float f; } c; c.i = ((uint)u) << 16; return c.f;
}
__device__ __forceinline__ float bits2f(uint b) {
    union { uint i; float f; } c; c.i = b; return c.f;
}
__device__ __forceinline__ ushort f2bf(float f) {
    union { float f; uint i; } c; c.f = f;
    uint b = c.i + 0x7fffu + ((c.i >> 16) & 1u);   // RNE, no NaN inputs here
    return (ushort)(b >> 16);
}

// ================= normalization + CSR build =================

__global__ void k_deg_init(float* deg, int* cnt, int n) {
    int i = blockIdx.x * blockDim.x + threadIdx.x;
    if (i < n) { deg[i] = 1.0f; cnt[i] = 0; }   // deg starts at 1.0 (self loop)
}

__global__ void k_deg_count(const int* __restrict__ col, const float* __restrict__ w,
                            float* __restrict__ deg, int* __restrict__ cnt, int E) {
    int i = blockIdx.x * blockDim.x + threadIdx.x;
    if (i < E) {
        int c = col[i];
        atomicAdd(&deg[c], w[i]);
        atomicAdd(&cnt[c], 1);
    }
}

__global__ void k_dinv(float* deg, int n) {
    int i = blockIdx.x * blockDim.x + threadIdx.x;
    if (i < n) {
        float d = deg[i];
        deg[i] = d > 0.0f ? rsqrtf(d) : 0.0f;
    }
}

__global__ void k_scan_bsum(const int* __restrict__ cnt, int* __restrict__ bsum, int N) {
    __shared__ int sdata[256];
    int base = blockIdx.x * 1024;
    int t = threadIdx.x;
    int s = 0;
    #pragma unroll
    for (int j = 0; j < 4; ++j) { int i = base + t * 4 + j; if (i < N) s += cnt[i]; }
    sdata[t] = s; __syncthreads();
    for (int off = 128; off > 0; off >>= 1) {
        if (t < off) sdata[t] += sdata[t + off];
        __syncthreads();
    }
    if (t == 0) bsum[blockIdx.x] = sdata[0];
}

__global__ void k_scan_boff(int* __restrict__ bsum, int nb, int* __restrict__ total) {
    __shared__ int buf[256];
    int t = threadIdx.x;
    int v = (t < nb) ? bsum[t] : 0;
    buf[t] = v; __syncthreads();
    for (int off = 1; off < 256; off <<= 1) {
        int x = (t >= off) ? buf[t - off] : 0;
        __syncthreads();
        buf[t] += x;
        __syncthreads();
    }
    if (t < nb) bsum[t] = buf[t] - v;
    if (t == nb - 1) *total = buf[t];
}

__global__ void k_scan_write(const int* __restrict__ cnt, const int* __restrict__ bsum,
                             int* __restrict__ rowptr, int* __restrict__ cursor, int N) {
    __shared__ int sdata[256];
    int base = blockIdx.x * 1024;
    int t = threadIdx.x;
    int c[4]; int s = 0;
    #pragma unroll
    for (int j = 0; j < 4; ++j) {
        int i = base + t * 4 + j;
        c[j] = (i < N) ? cnt[i] : 0;
        s += c[j];
    }
    sdata[t] = s; __syncthreads();
    for (int off = 1; off < 256; off <<= 1) {
        int x = (t >= off) ? sdata[t - off] : 0;
        __syncthreads();
        sdata[t] += x;
        __syncthreads();
    }
    int excl = sdata[t] - s + bsum[blockIdx.x];
    #pragma unroll
    for (int j = 0; j < 4; ++j) {
        int i = base + t * 4 + j;
        if (i < N) { rowptr[i] = excl; cursor[i] = excl; }
        excl += c[j];
    }
}

// Scatter edges into dst-sorted CSR as packed records: low16 = src row (N<=65536),
// high16 = bf16(norm).
__global__ void k_scatter(const int* __restrict__ row, const int* __restrict__ col,
                          const float* __restrict__ w, const float* __restrict__ dinv,
                          int* __restrict__ cursor, uint* __restrict__ edges, int E) {
    int i = blockIdx.x * blockDim.x + threadIdx.x;
    if (i < E) {
        int r = row[i], c = col[i];
        int p = atomicAdd(&cursor[c], 1);
        float nv = dinv[r] * w[i] * dinv[c];
        edges[p] = (uint)(ushort)r | ((uint)f2bf(nv) << 16);
    }
}

// ================= weight split + transpose: W[K][N] -> WT{h,l}[N][K] ==========
__global__ void k_splitT(const float* __restrict__ W, ushort* __restrict__ Th,
                         ushort* __restrict__ Tl, int K, int N) {
    int i = blockIdx.x * 256 + threadIdx.x;
    if (i < K * N) {
        int k = i / N, n = i - k * N;
        float v = W[i];
        ushort hi = f2bf(v);
        ushort lo = f2bf(v - bf2f(hi));
        Th[(size_t)n * K + k] = hi;
        Tl[(size_t)n * K + k] = lo;
    }
}

// ================= MFMA GEMM: h_pan[panel][m][32] = bf16(A_f32[M,K] @ W[K,Nc]) ==
// Tile 128x128, BK=32, 256 thr = 4 waves (2x2), wave = 64x64 = 4x4 MFMA tiles.
// 3-product split precision: Ah*Bh + Ah*Bl + Al*Bh.
#define LDA 40   // padded LDS row stride (bf16 elems); 80 B = 5*16 keeps 16B align

__global__ __launch_bounds__(256)
void k_gemm3(const float* __restrict__ A, const ushort* __restrict__ BTh,
             const ushort* __restrict__ BTl, ushort* __restrict__ Cpan,
             int M, int Nc, int K) {
    __shared__ __align__(16) ushort As[2][128][LDA];
    __shared__ __align__(16) ushort Bs[2][128][LDA];

    const int t    = threadIdx.x;
    const int lane = t & 63;
    const int wid  = t >> 6;
    const int wm   = wid >> 1;
    const int wn   = wid & 1;
    const int ml   = lane & 15;
    const int kq   = lane >> 4;
    const int bm   = blockIdx.y * 128;
    const int bn   = blockIdx.x * 128;

    f32x4 acc[4][4];
    #pragma unroll
    for (int mt = 0; mt < 4; ++mt)
        #pragma unroll
        for (int nt = 0; nt < 4; ++nt) acc[mt][nt] = (f32x4){0.f, 0.f, 0.f, 0.f};

    for (int k0 = 0; k0 < K; k0 += 32) {
        // stage A (fp32 -> bf16 hi/lo), 128x32
        #pragma unroll
        for (int it = 0; it < 4; ++it) {
            int idx = (t + it * 256) * 4;
            int r  = idx >> 5;
            int kk = idx & 31;
            int grow = bm + r;
            f32x4 v = (f32x4){0.f, 0.f, 0.f, 0.f};
            if (grow < M) v = *(const f32x4*)&A[(size_t)grow * K + k0 + kk];
            us4 hi, lo;
            #pragma unroll
            for (int j = 0; j < 4; ++j) {
                ushort h = f2bf(v[j]);
                hi[j] = h;
                lo[j] = f2bf(v[j] - bf2f(h));
            }
            *(us4*)&As[0][r][kk] = hi;
            *(us4*)&As[1][r][kk] = lo;
        }
        // stage B (pre-split bf16), 128x32 per half
        #pragma unroll
        for (int it = 0; it < 2; ++it) {
            int idx = (t + it * 256) * 8;
            int n  = idx >> 5;
            int kk = idx & 31;
            u32x4 vh = *(const u32x4*)&BTh[(size_t)(bn + n) * K + k0 + kk];
            *(u32x4*)&Bs[0][n][kk] = vh;
            u32x4 vl = *(const u32x4*)&BTl[(size_t)(bn + n) * K + k0 + kk];
            *(u32x4*)&Bs[1][n][kk] = vl;
        }
        __syncthreads();

        short8 a[4][2], b[4][2];
        #pragma unroll
        for (int mt = 0; mt < 4; ++mt) {
            a[mt][0] = *(const short8*)&As[0][wm * 64 + mt * 16 + ml][kq * 8];
            a[mt][1] = *(const short8*)&As[1][wm * 64 + mt * 16 + ml][kq * 8];
        }
        #pragma unroll
        for (int nt = 0; nt < 4; ++nt) {
            b[nt][0] = *(const short8*)&Bs[0][wn * 64 + nt * 16 + ml][kq * 8];
            b[nt][1] = *(const short8*)&Bs[1][wn * 64 + nt * 16 + ml][kq * 8];
        }
        #pragma unroll
        for (int mt = 0; mt < 4; ++mt)
            #pragma unroll
            for (int nt = 0; nt < 4; ++nt) {
                acc[mt][nt] = __builtin_amdgcn_mfma_f32_16x16x32_bf16(a[mt][0], b[nt][0], acc[mt][nt], 0, 0, 0);
                acc[mt][nt] = __builtin_amdgcn_mfma_f32_16x16x32_bf16(a[mt][0], b[nt][1], acc[mt][nt], 0, 0, 0);
                acc[mt][nt] = __builtin_amdgcn_mfma_f32_16x16x32_bf16(a[mt][1], b[nt][0], acc[mt][nt], 0, 0, 0);
            }
        __syncthreads();
    }

    // epilogue: C/D layout col=lane&15, row=(lane>>4)*4+reg; panel-major store
    #pragma unroll
    for (int mt = 0; mt < 4; ++mt) {
        int rbase = bm + wm * 64 + mt * 16 + kq * 4;
        #pragma unroll
        for (int nt = 0; nt < 4; ++nt) {
            int colg = bn + wn * 64 + nt * 16 + ml;
            size_t pbase = (size_t)(colg >> 5) * M * 32 + (colg & 31);
            #pragma unroll
            for (int r = 0; r < 4; ++r) {
                int rr = rbase + r;
                if (rr < M) Cpan[pbase + (size_t)rr * 32] = f2bf(acc[mt][nt][r]);
            }
        }
    }
}

// ================= panel CSR aggregation ======================================
// h_pan: [npan][N][32] bf16. out: row-major [N][F] fp32.
// Lanes: sub=lane>>2 (16 edges in flight per wave instr), q=lane&3 (8 features,
// one 16B dwordx4 gather per lane). Simple loop — compiler pipelines it.
#define NODES_PER_CHUNK 16

template <bool RELU>
__device__ __forceinline__
void aggr_body(const int* __restrict__ rowptr, const uint* __restrict__ edges,
               const ushort* __restrict__ hpan, const float* __restrict__ dinv,
               const float* __restrict__ bias, float* __restrict__ out,
               int F, int npan, int N) {
    const int bid   = blockIdx.x;
    const int p     = bid % npan;
    const int chunk = bid / npan;
    const int wave  = threadIdx.x >> 6;
    const int lane  = threadIdx.x & 63;
    const int sub   = lane >> 2;       // 0..15
    const int q     = lane & 3;        // 0..3 -> 8 features

    const ushort* hp = hpan + (size_t)p * N * 32;
    const int fbase = p * 32 + q * 8;
    f32x4 bv0 = *(const f32x4*)&bias[fbase];
    f32x4 bv1 = *(const f32x4*)&bias[fbase + 4];

    #pragma unroll
    for (int i = 0; i < NODES_PER_CHUNK / 4; ++i) {
        int node = chunk * NODES_PER_CHUNK + i * 4 + wave;
        if (node >= N) return;
        int beg = rowptr[node], end = rowptr[node + 1];

        float acc[8] = {};
        for (int e = beg + sub; e < end; e += 16) {
            uint pk = edges[e];
            float nv = bits2f(pk & 0xffff0000u);
            int r = (int)(pk & 0xffffu);
            u32x4 hv = *(const u32x4*)&hp[(size_t)r * 32 + q * 8];
            #pragma unroll
            for (int j = 0; j < 4; ++j) {
                uint w = hv[j];
                acc[2 * j]     += nv * bits2f(w << 16);
                acc[2 * j + 1] += nv * bits2f(w & 0xffff0000u);
            }
        }
        // butterfly over sub (lane bits 2..5)
        #pragma unroll
        for (int m = 4; m <= 32; m <<= 1) {
            #pragma unroll
            for (int j = 0; j < 8; ++j) acc[j] += __shfl_xor(acc[j], m, 64);
        }
        if (sub == 0) {
            float di = dinv[node];
            float d2 = di * di;
            u32x4 hs = *(const u32x4*)&hp[(size_t)node * 32 + q * 8];
            f32x4 v0, v1;
            #pragma unroll
            for (int j = 0; j < 4; ++j) {
                uint w = hs[j];
                float lo = bits2f(w << 16);
                float hi = bits2f(w & 0xffff0000u);
                float r0 = acc[2 * j]     + d2 * lo + ((j < 2) ? bv0[2 * j]     : bv1[2 * j - 4]);
                float r1 = acc[2 * j + 1] + d2 * hi + ((j < 2) ? bv0[2 * j + 1] : bv1[2 * j - 3]);
                if (RELU) { r0 = fmaxf(r0, 0.f); r1 = fmaxf(r1, 0.f); }
                if (j < 2) { v0[2 * j] = r0; v0[2 * j + 1] = r1; }
                else       { v1[2 * j - 4] = r0; v1[2 * j - 3] = r1; }
            }
            *(f32x4*)&out[(size_t)node * F + fbase] = v0;
            *(f32x4*)&out[(size_t)node * F + fbase + 4] = v1;
        }
    }
}

__global__ __launch_bounds__(256)
void k_aggr1(const int* __restrict__ rowptr, const uint* __restrict__ edges,
             const ushort* __restrict__ hpan, const float* __restrict__ dinv,
             const float* __restrict__ bias, float* __restrict__ out,
             int F, int npan, int N) {
    aggr_body<true>(rowptr, edges, hpan, dinv, bias, out, F, npan, N);
}

__global__ __launch_bounds__(256)
void k_aggr2(const int* __restrict__ rowptr, const uint* __restrict__ edges,
             const ushort* __restrict__ hpan, const float* __restrict__ dinv,
             const float* __restrict__ bias, float* __restrict__ out,
             int F, int npan, int N) {
    aggr_body<false>(rowptr, edges, hpan, dinv, bias, out, F, npan, N);
}

// ================= launcher =================

static inline char* bump(char*& p, size_t bytes) {
    char* r = p;
    p += (bytes + 255) & ~(size_t)255;
    return r;
}

extern "C" void kernel_launch(void* const* d_in, const int* in_sizes, int n_in,
                              void* d_out, int out_size, void* d_ws, size_t ws_size,
                              hipStream_t stream) {
    const float* x  = (const float*)d_in[0];
    const int*   ei = (const int*)d_in[1];
    const float* ew = (const float*)d_in[2];
    const float* W1 = (const float*)d_in[3];
    const float* b1 = (const float*)d_in[4];
    const float* W2 = (const float*)d_in[5];
    const float* b2 = (const float*)d_in[6];
    float* out = (float*)d_out;

    const int E    = in_sizes[2];
    const int H    = in_sizes[4];       // 256
    const int Fout = in_sizes[6];       // 128
    const int Fin  = in_sizes[3] / H;   // 256
    const int N    = in_sizes[0] / Fin; // 50000 (fits ushort)

    const int* row = ei;
    const int* col = ei + E;

    char* p = (char*)d_ws;
    float*  dinv   = (float*)bump(p, (size_t)N * 4);
    int*    rowptr = (int*)bump(p, (size_t)(N + 1) * 4);
    int*    cursor = (int*)bump(p, (size_t)N * 4);
    int*    cnt    = (int*)bump(p, (size_t)N * 4);
    uint*   edges  = (uint*)bump(p, (size_t)E * 4);
    ushort* WT1h   = (ushort*)bump(p, (size_t)Fin * H * 2);
    ushort* WT1l   = (ushort*)bump(p, (size_t)Fin * H * 2);
    ushort* WT2h   = (ushort*)bump(p, (size_t)H * Fout * 2);
    ushort* WT2l   = (ushort*)bump(p, (size_t)H * Fout * 2);
    ushort* h1     = (ushort*)bump(p, (size_t)N * H * 2);     // panel-major bf16
    float*  a1     = (float*)bump(p, (size_t)N * H * 4);      // row-major fp32
    ushort* h2     = (ushort*)bump(p, (size_t)N * Fout * 2);  // panel-major bf16

    const int nb = (N + 1023) / 1024;

    k_deg_init<<<(N + 255) / 256, 256, 0, stream>>>(dinv, cnt, N);
    k_deg_count<<<(E + 255) / 256, 256, 0, stream>>>(col, ew, dinv, cnt, E);
    k_dinv<<<(N + 255) / 256, 256, 0, stream>>>(dinv, N);

    k_splitT<<<(Fin * H + 255) / 256, 256, 0, stream>>>(W1, WT1h, WT1l, Fin, H);
    k_splitT<<<(H * Fout + 255) / 256, 256, 0, stream>>>(W2, WT2h, WT2l, H, Fout);

    k_scan_bsum<<<nb, 256, 0, stream>>>(cnt, cursor, N);
    k_scan_boff<<<1, 256, 0, stream>>>(cursor, nb, rowptr + N);
    k_scan_write<<<nb, 256, 0, stream>>>(cnt, cursor, rowptr, cnt, N);
    k_scatter<<<(E + 255) / 256, 256, 0, stream>>>(row, col, ew, dinv, cnt, edges, E);

    const int chunks = (N + NODES_PER_CHUNK - 1) / NODES_PER_CHUNK;

    // layer 1
    k_gemm3<<<dim3(H / 128, (N + 127) / 128), 256, 0, stream>>>(x, WT1h, WT1l, h1, N, H, Fin);
    k_aggr1<<<chunks * (H / 32), 256, 0, stream>>>(rowptr, edges, h1, dinv, b1, a1, H, H / 32, N);

    // layer 2
    k_gemm3<<<dim3(Fout / 128, (N + 127) / 128), 256, 0, stream>>>(a1, WT2h, WT2l, h2, N, Fout, H);
    k_aggr2<<<chunks * (Fout / 32), 256, 0, stream>>>(rowptr, edges, h2, dinv, b2, out, Fout, Fout / 32, N);
}